// Round 11
// baseline (299.511 us; speedup 1.0000x reference)
//
#include <hip/hip_runtime.h>
#include <math.h>

#define NTOK 16384      // 4 * 4096 tokens
#define DIM 2048
#define NEXP 64
#define TOPK 8
#define BT 64           // tokens per block (lane = token)
#define KC 64           // four numpy 16-blocks per stage
#define NCHUNK (DIM / KC)   // 32
#define PADK 68         // LDS row stride floats; granule stride 17 (odd) -> uniform banks
#define NBLK (NTOK / BT)    // 256 blocks, 1/CU, 16 waves/CU = 4/SIMD
#define EPW 4           // experts per wave (16 waves x 4 = 64)

typedef float f2 __attribute__((ext_vector_type(2)));
typedef float f4 __attribute__((ext_vector_type(4)));

// VOP3P packed f32: two independent IEEE f32 ops per instr, component-wise
// bit-identical to the scalar sequence they replace.
__device__ __forceinline__ f2 pk_mul(f2 a, f2 b) {
    f2 d; asm("v_pk_mul_f32 %0, %1, %2" : "=v"(d) : "v"(a), "v"(b)); return d;
}
__device__ __forceinline__ f2 pk_add(f2 a, f2 b) {
    f2 d; asm("v_pk_add_f32 %0, %1, %2" : "=v"(d) : "v"(a), "v"(b)); return d;
}

__global__ __launch_bounds__(1024, 1) void moe_gate_np(
    const float* __restrict__ h, const float* __restrict__ W,
    float* __restrict__ out, float* __restrict__ wsum)
{
#pragma clang fp contract(off)
    __shared__ float sA[BT * PADK];          // h tile [64][68]  (17.4 KB)
    __shared__ float lg[BT][NEXP + 2];       // logits -> p values (16.9 KB)

    const int tid  = threadIdx.x;            // 0..1023
    const int lane = tid & 63;               // token within tile
    const int wv   = tid >> 6;               // 0..15: expert quartet
    const int blk  = blockIdx.x;
    const long tok0 = (long)blk * BT;
    const float* hA = h + tok0 * DIM;

    const int e0 = wv * EPW;

    // Opaque per-lane zero: defeats uniformity analysis so W accesses become
    // VMEM global_load_dwordx4 (broadcast-coalesced, vmcnt-pipelineable)
    // instead of s_load (SMEM, lgkmcnt(0)-serialized against ds_read).
    int vzero; asm("v_mov_b32 %0, 0" : "=v"(vzero));
    const float* wb = W + (long)e0 * DIM + vzero;

    // ---- A staging map: 1 f4 per thread per stage ----
    const int rs = tid >> 4;                 // 0..63
    const int cs = (tid & 15) * 4;           // 0..60
    f4 pa = *(const f4*)(hA + (long)rs * DIM + cs);

    // accumulators: 4 experts x chain pairs (c0,c1) and (c2,c3)
    f2 acc01[EPW], acc23[EPW];
    #pragma unroll
    for (int j = 0; j < EPW; ++j) { acc01[j] = (f2)(0.f); acc23[j] = (f2)(0.f); }

    for (int kc = 0; kc < NCHUNK; ++kc) {
        __syncthreads();
        *(f4*)&sA[rs * PADK + cs] = pa;
        __syncthreads();

        if (kc + 1 < NCHUNK) {               // prefetch next A stage under compute
            const long ko = (long)(kc + 1) * KC;
            pa = *(const f4*)(hA + (long)rs * DIM + ko + cs);
        }

        const float* wk = wb + (long)kc * KC;

        // 4 numpy 16-blocks per stage, strictly ascending k
        #pragma unroll
        for (int s = 0; s < 4; ++s) {
            // B batch: 4 experts x 4 f4, uniform addr -> broadcast VMEM loads
            f4 B[EPW][4];
            #pragma unroll
            for (int j = 0; j < EPW; ++j)
                #pragma unroll
                for (int q = 0; q < 4; ++q)
                    B[j][q] = *(const f4*)(wk + (long)j * DIM + s * 16 + 4 * q);

            // A: this lane's token, 16 k-values (4 x ds_read_b128)
            f4 af[4];
            const float* ab = &sA[lane * PADK + s * 16];
            #pragma unroll
            for (int v = 0; v < 4; ++v) af[v] = *(const f4*)(ab + 4 * v);

            f2 alo[4], ahi[4];               // .xy -> chains 0,1 ; .zw -> chains 2,3
            #pragma unroll
            for (int v = 0; v < 4; ++v) {
                alo[v] = __builtin_shufflevector(af[v], af[v], 0, 1);
                ahi[v] = __builtin_shufflevector(af[v], af[v], 2, 3);
            }

            #pragma unroll
            for (int j = 0; j < EPW; ++j) {
                f2 blo[4], bhi[4];
                #pragma unroll
                for (int v = 0; v < 4; ++v) {
                    blo[v] = __builtin_shufflevector(B[j][v], B[j][v], 0, 1);
                    bhi[v] = __builtin_shufflevector(B[j][v], B[j][v], 2, 3);
                }
                f2 t;
                // chains 0,1: c = p0 + (p1 + (p2 + (p3 + c)))
                t = pk_add(pk_mul(blo[3], alo[3]), acc01[j]);
                t = pk_add(pk_mul(blo[2], alo[2]), t);
                t = pk_add(pk_mul(blo[1], alo[1]), t);
                acc01[j] = pk_add(pk_mul(blo[0], alo[0]), t);
                // chains 2,3
                t = pk_add(pk_mul(bhi[3], ahi[3]), acc23[j]);
                t = pk_add(pk_mul(bhi[2], ahi[2]), t);
                t = pk_add(pk_mul(bhi[1], ahi[1]), t);
                acc23[j] = pk_add(pk_mul(bhi[0], ahi[0]), t);
            }
        }
    }

    // horizontal combine: (c0+c2)+(c1+c3)  (npyv_sum_f32 SSE2 order)
    #pragma unroll
    for (int j = 0; j < EPW; ++j) {
        f2 s2 = pk_add(acc01[j], acc23[j]);   // (c0+c2, c1+c3)
        lg[lane][e0 + j] = s2.x + s2.y;
    }
    __syncthreads();

    // ---- per-token f32 softmax + stable top-8, numpy rounding orders ----
    float auxacc = 0.f;

    for (int tt = 0; tt < 4; ++tt) {
        const int t = wv * 4 + tt;            // 16 waves x 4 tokens
        const float s = lg[t][lane];          // lane = expert here

        float m = s;                          // max: exact, order-independent
        #pragma unroll
        for (int off = 32; off >= 1; off >>= 1)
            m = fmaxf(m, __shfl_xor(m, off));

        const float p = expf(s - m);
        lg[t][lane] = p;                      // own wave's rows only
        __asm__ volatile("" ::: "memory");    // compiler barrier; DS in-order per wave

        // np.sum pairwise, n=64: 8 stride-8 serial chains + fixed combine
        float r0s = lg[t][0], r1s = lg[t][1], r2s = lg[t][2], r3s = lg[t][3];
        float r4s = lg[t][4], r5s = lg[t][5], r6s = lg[t][6], r7s = lg[t][7];
        #pragma unroll
        for (int i = 1; i < 8; ++i) {
            r0s += lg[t][8 * i + 0]; r1s += lg[t][8 * i + 1];
            r2s += lg[t][8 * i + 2]; r3s += lg[t][8 * i + 3];
            r4s += lg[t][8 * i + 4]; r5s += lg[t][8 * i + 5];
            r6s += lg[t][8 * i + 6]; r7s += lg[t][8 * i + 7];
        }
        const float S = ((r0s + r1s) + (r2s + r3s)) + ((r4s + r5s) + (r6s + r7s));

        const float score = p / S;            // IEEE f32 divide, matches np
        auxacc += score;

        // stable top-8: max with lowest-index tie-break (stable argsort)
        float cv = score;
        float myv = 0.f;
        int   myi = 0;
        #pragma unroll
        for (int i = 0; i < TOPK; ++i) {
            float v = cv;
            int idx = lane;
            #pragma unroll
            for (int off = 32; off >= 1; off >>= 1) {
                float v2 = __shfl_xor(v, off);
                int   i2 = __shfl_xor(idx, off);
                if (v2 > v || (v2 == v && i2 < idx)) { v = v2; idx = i2; }
            }
            if (lane == i)   { myv = v; myi = idx; }
            if (lane == idx) cv = -1.f;       // scores >= 0
        }

        // weight denom: np.sum n=8 -> serial ascending
        float S8 = 0.f;
        #pragma unroll
        for (int r = 0; r < TOPK; ++r) S8 += __shfl(myv, r);

        if (lane < TOPK) {
            const long o = (tok0 + t) * TOPK + lane;
            out[o]                     = (float)myi;   // expert_ids
            out[(long)NTOK * TOPK + o] = myv / S8;     // expert_weight
        }
    }

    const int b = blk >> 6;                  // 64 blocks per batch row
    atomicAdd(&wsum[b * NEXP + lane], auxacc);
}

__global__ void aux_finish(const float* __restrict__ wsum, float* __restrict__ out)
{
    const int lane = threadIdx.x;            // 64 threads
    float a = 0.f;
    #pragma unroll
    for (int b = 0; b < 4; ++b) {
        const float v = wsum[b * NEXP + lane] * (1.0f / 4096.0f);
        a = fmaf(v, v, a);
    }
    #pragma unroll
    for (int off = 32; off >= 1; off >>= 1)
        a += __shfl_xor(a, off);
    if (lane == 0)
        out[2L * NTOK * TOPK] = a * 0.25f * (float)NEXP * 0.01f;
}

extern "C" void kernel_launch(void* const* d_in, const int* in_sizes, int n_in,
                              void* d_out, int out_size, void* d_ws, size_t ws_size,
                              hipStream_t stream) {
    const float* h = (const float*)d_in[0];
    const float* W = (const float*)d_in[1];
    float* out  = (float*)d_out;
    float* wsum = (float*)d_ws;              // 256 f32

    hipMemsetAsync(d_ws, 0, 1024, stream);
    moe_gate_np<<<NBLK, 1024, 0, stream>>>(h, W, out, wsum);
    aux_finish<<<1, 64, 0, stream>>>(wsum, out);
}

// Round 12
// 224.582 us; speedup vs baseline: 1.3336x; 1.3336x over previous
//
#include <hip/hip_runtime.h>
#include <math.h>

#define NTOK 16384      // 4 * 4096 tokens
#define DIM 2048
#define NEXP 64
#define TOPK 8
#define BT 64           // tokens per block (lane = token)
#define KC 64           // four numpy 16-blocks per stage
#define NCHUNK (DIM / KC)   // 32
#define PADK 68         // LDS row stride floats; granule stride 17 (odd) -> uniform banks
#define NBLK (NTOK / BT)    // 256 blocks, 1/CU, 16 waves/CU = 4/SIMD
#define EPW 2           // experts per wave per pass
#define NPASS 2         // 16 waves x 2 experts x 2 passes = 64 experts

typedef float f2 __attribute__((ext_vector_type(2)));
typedef float f4 __attribute__((ext_vector_type(4)));

// VOP3P packed f32: two independent IEEE f32 ops per instr, component-wise
// bit-identical to the scalar sequence they replace.
__device__ __forceinline__ f2 pk_mul(f2 a, f2 b) {
    f2 d; asm("v_pk_mul_f32 %0, %1, %2" : "=v"(d) : "v"(a), "v"(b)); return d;
}
__device__ __forceinline__ f2 pk_add(f2 a, f2 b) {
    f2 d; asm("v_pk_add_f32 %0, %1, %2" : "=v"(d) : "v"(a), "v"(b)); return d;
}

__global__ __launch_bounds__(1024, 1) void moe_gate_np(
    const float* __restrict__ h, const float* __restrict__ W,
    float* __restrict__ out, float* __restrict__ wsum)
{
#pragma clang fp contract(off)
    __shared__ float sA[BT * PADK];          // h tile [64][68]  (17.4 KB)
    __shared__ float lg[BT][NEXP + 2];       // logits -> p values (16.9 KB)

    const int tid  = threadIdx.x;            // 0..1023
    const int lane = tid & 63;               // token within tile
    const int wv   = tid >> 6;               // 0..15
    const int blk  = blockIdx.x;
    const long tok0 = (long)blk * BT;
    const float* hA = h + tok0 * DIM;

    // ---- A staging map: 1 f4 per thread per stage ----
    const int rs = tid >> 4;                 // 0..63
    const int cs = (tid & 15) * 4;           // 0..60

    const int wvu = __builtin_amdgcn_readfirstlane(wv);   // uniform wave id

    for (int pass = 0; pass < NPASS; ++pass) {
        const int e0 = wvu * EPW + pass * (NEXP / NPASS);  // expert pair base
        const float* wb = W + (long)e0 * DIM;              // uniform -> s_load

        f4 pa = *(const f4*)(hA + (long)rs * DIM + cs);    // stage-0 A prefetch

        // accumulators: 2 experts x chain pairs (c0,c1)/(c2,c3)
        f2 a01[EPW], a23[EPW];
        #pragma unroll
        for (int j = 0; j < EPW; ++j) { a01[j] = (f2)(0.f); a23[j] = (f2)(0.f); }

        // B ping-pong (wave-uniform -> SGPRs, 2x32 = 64 SGPR)
        f4 Bf[2][EPW][4];
        #pragma unroll
        for (int j = 0; j < EPW; ++j)
            #pragma unroll
            for (int q = 0; q < 4; ++q)
                Bf[0][j][q] = *(const f4*)(wb + (long)j * DIM + 4 * q);  // kb=0

        f4 af[2][4];                          // A ping-pong (VGPRs)

        for (int kc = 0; kc < NCHUNK; ++kc) {
            __syncthreads();
            *(f4*)&sA[rs * PADK + cs] = pa;
            __syncthreads();
            if (kc + 1 < NCHUNK)              // next-stage A staging prefetch
                pa = *(const f4*)(hA + (long)rs * DIM + (long)(kc + 1) * KC + cs);

            const float* ab = &sA[lane * PADK];
            #pragma unroll
            for (int v = 0; v < 4; ++v) af[0][v] = *(const f4*)(ab + 4 * v);

            #pragma unroll
            for (int s = 0; s < 4; ++s) {
                const int cur = s & 1, nxt = cur ^ 1;

                // prefetch A(s+1) within stage (ds_read, in flight over MACs)
                if (s < 3) {
                    #pragma unroll
                    for (int v = 0; v < 4; ++v)
                        af[nxt][v] = *(const f4*)(ab + (s + 1) * 16 + 4 * v);
                }
                // prefetch B(next 16-block), clamped at the last block
                {
                    int kb = kc * KC + s * 16 + 16;
                    if (kb > DIM - 16) kb = DIM - 16;
                    #pragma unroll
                    for (int j = 0; j < EPW; ++j)
                        #pragma unroll
                        for (int q = 0; q < 4; ++q)
                            Bf[nxt][j][q] = *(const f4*)(wb + (long)j * DIM + kb + 4 * q);
                }

                // MACs: numpy chains, strictly ascending k
                f2 alo[4], ahi[4];
                #pragma unroll
                for (int v = 0; v < 4; ++v) {
                    alo[v] = __builtin_shufflevector(af[cur][v], af[cur][v], 0, 1);
                    ahi[v] = __builtin_shufflevector(af[cur][v], af[cur][v], 2, 3);
                }
                #pragma unroll
                for (int j = 0; j < EPW; ++j) {
                    f2 blo[4], bhi[4];
                    #pragma unroll
                    for (int v = 0; v < 4; ++v) {
                        blo[v] = __builtin_shufflevector(Bf[cur][j][v], Bf[cur][j][v], 0, 1);
                        bhi[v] = __builtin_shufflevector(Bf[cur][j][v], Bf[cur][j][v], 2, 3);
                    }
                    f2 t;
                    // chains 0,1: c = p0 + (p1 + (p2 + (p3 + c)))
                    t = pk_add(pk_mul(blo[3], alo[3]), a01[j]);
                    t = pk_add(pk_mul(blo[2], alo[2]), t);
                    t = pk_add(pk_mul(blo[1], alo[1]), t);
                    a01[j] = pk_add(pk_mul(blo[0], alo[0]), t);
                    // chains 2,3
                    t = pk_add(pk_mul(bhi[3], ahi[3]), a23[j]);
                    t = pk_add(pk_mul(bhi[2], ahi[2]), t);
                    t = pk_add(pk_mul(bhi[1], ahi[1]), t);
                    a23[j] = pk_add(pk_mul(bhi[0], ahi[0]), t);
                }
            }
        }

        // horizontal combine: (c0+c2)+(c1+c3)  (npyv_sum_f32 SSE2 order)
        #pragma unroll
        for (int j = 0; j < EPW; ++j) {
            f2 s2 = pk_add(a01[j], a23[j]);   // (c0+c2, c1+c3)
            lg[lane][e0 + j] = s2.x + s2.y;
        }
    }
    __syncthreads();

    // ---- per-token f32 softmax + stable top-8, numpy rounding orders ----
    float auxacc = 0.f;

    for (int tt = 0; tt < 4; ++tt) {
        const int t = wv * 4 + tt;            // 16 waves x 4 tokens
        const float s = lg[t][lane];          // lane = expert here

        float m = s;                          // max: exact, order-independent
        #pragma unroll
        for (int off = 32; off >= 1; off >>= 1)
            m = fmaxf(m, __shfl_xor(m, off));

        const float p = expf(s - m);
        lg[t][lane] = p;                      // own wave's rows only
        __asm__ volatile("" ::: "memory");    // compiler barrier; DS in-order per wave

        // np.sum pairwise, n=64: 8 stride-8 serial chains + fixed combine
        float r0s = lg[t][0], r1s = lg[t][1], r2s = lg[t][2], r3s = lg[t][3];
        float r4s = lg[t][4], r5s = lg[t][5], r6s = lg[t][6], r7s = lg[t][7];
        #pragma unroll
        for (int i = 1; i < 8; ++i) {
            r0s += lg[t][8 * i + 0]; r1s += lg[t][8 * i + 1];
            r2s += lg[t][8 * i + 2]; r3s += lg[t][8 * i + 3];
            r4s += lg[t][8 * i + 4]; r5s += lg[t][8 * i + 5];
            r6s += lg[t][8 * i + 6]; r7s += lg[t][8 * i + 7];
        }
        const float S = ((r0s + r1s) + (r2s + r3s)) + ((r4s + r5s) + (r6s + r7s));

        const float score = p / S;            // IEEE f32 divide, matches np
        auxacc += score;

        // stable top-8: max with lowest-index tie-break (stable argsort)
        float cv = score;
        float myv = 0.f;
        int   myi = 0;
        #pragma unroll
        for (int i = 0; i < TOPK; ++i) {
            float v = cv;
            int idx = lane;
            #pragma unroll
            for (int off = 32; off >= 1; off >>= 1) {
                float v2 = __shfl_xor(v, off);
                int   i2 = __shfl_xor(idx, off);
                if (v2 > v || (v2 == v && i2 < idx)) { v = v2; idx = i2; }
            }
            if (lane == i)   { myv = v; myi = idx; }
            if (lane == idx) cv = -1.f;       // scores >= 0
        }

        // weight denom: np.sum n=8 -> serial ascending
        float S8 = 0.f;
        #pragma unroll
        for (int r = 0; r < TOPK; ++r) S8 += __shfl(myv, r);

        if (lane < TOPK) {
            const long o = (tok0 + t) * TOPK + lane;
            out[o]                     = (float)myi;   // expert_ids
            out[(long)NTOK * TOPK + o] = myv / S8;     // expert_weight
        }
    }

    const int b = blk >> 6;                  // 64 blocks per batch row
    atomicAdd(&wsum[b * NEXP + lane], auxacc);
}

__global__ void aux_finish(const float* __restrict__ wsum, float* __restrict__ out)
{
    const int lane = threadIdx.x;            // 64 threads
    float a = 0.f;
    #pragma unroll
    for (int b = 0; b < 4; ++b) {
        const float v = wsum[b * NEXP + lane] * (1.0f / 4096.0f);
        a = fmaf(v, v, a);
    }
    #pragma unroll
    for (int off = 32; off >= 1; off >>= 1)
        a += __shfl_xor(a, off);
    if (lane == 0)
        out[2L * NTOK * TOPK] = a * 0.25f * (float)NEXP * 0.01f;
}

extern "C" void kernel_launch(void* const* d_in, const int* in_sizes, int n_in,
                              void* d_out, int out_size, void* d_ws, size_t ws_size,
                              hipStream_t stream) {
    const float* h = (const float*)d_in[0];
    const float* W = (const float*)d_in[1];
    float* out  = (float*)d_out;
    float* wsum = (float*)d_ws;              // 256 f32

    hipMemsetAsync(d_ws, 0, 1024, stream);
    moe_gate_np<<<NBLK, 1024, 0, stream>>>(h, W, out, wsum);
    aux_finish<<<1, 64, 0, stream>>>(wsum, out);
}

// Round 13
// 164.041 us; speedup vs baseline: 1.8258x; 1.3691x over previous
//
#include <hip/hip_runtime.h>
#include <math.h>

#define NTOK 16384      // 4 * 4096 tokens
#define DIM 2048
#define NEXP 64
#define TOPK 8
#define BT 64           // tokens per tile (lane = token)
#define KC 64           // four numpy 16-blocks per stage
#define NCHUNK (DIM / KC)   // 32
#define PADK 68         // LDS row stride floats
#define EPW 4           // experts per wave

typedef float f2 __attribute__((ext_vector_type(2)));
typedef float f4 __attribute__((ext_vector_type(4)));

// VOP3P packed f32: two independent IEEE f32 ops per instr, component-wise
// bit-identical to the scalar sequence they replace.
__device__ __forceinline__ f2 pk_mul_sv(f2 bs, f2 av) {
    f2 d; asm("v_pk_mul_f32 %0, %1, %2" : "=v"(d) : "s"(bs), "v"(av)); return d;
}
__device__ __forceinline__ f2 pk_add(f2 a, f2 b) {
    f2 d; asm("v_pk_add_f32 %0, %1, %2" : "=v"(d) : "v"(a), "v"(b)); return d;
}

// ---------- split path kernel 1: GEMM -> global logits ----------
// grid 512 = 256 token-tiles x 2 expert-halves; 512 thr = 8 waves; 2 blocks/CU.
__global__ __launch_bounds__(512, 4) void moe_gemm(
    const float* __restrict__ h, const float* __restrict__ W,
    float* __restrict__ lgout)
{
#pragma clang fp contract(off)
    __shared__ float sA[2][BT * PADK];       // double-buffered h tile, 34.8 KB

    const int tid  = threadIdx.x;            // 0..511
    const int lane = tid & 63;               // token within tile
    const int wv   = tid >> 6;               // 0..7
    const int tile = blockIdx.x >> 1;
    const int hf   = blockIdx.x & 1;         // expert half
    const long tok0 = (long)tile * BT;
    const float* hA = h + tok0 * DIM;

    const int e0 = __builtin_amdgcn_readfirstlane(hf * 32 + wv * EPW);
    const float* wb = W + (long)e0 * DIM;    // uniform -> s_load

    // staging map: 2 f4 per thread per stage (64 rows x 64 cols)
    const int rs0 = tid >> 4;                // 0..31
    const int cs0 = (tid & 15) * 4;          // 0..60

    // stage 0: load + write buf0; prefetch stage 1 into regs
    f4 ra = *(const f4*)(hA + (long)rs0 * DIM + cs0);
    f4 rb = *(const f4*)(hA + (long)(rs0 + 32) * DIM + cs0);
    *(f4*)&sA[0][rs0 * PADK + cs0]        = ra;
    *(f4*)&sA[0][(rs0 + 32) * PADK + cs0] = rb;
    ra = *(const f4*)(hA + (long)rs0 * DIM + KC + cs0);
    rb = *(const f4*)(hA + (long)(rs0 + 32) * DIM + KC + cs0);

    f2 a01[EPW], a23[EPW];
    #pragma unroll
    for (int j = 0; j < EPW; ++j) { a01[j] = (f2)(0.f); a23[j] = (f2)(0.f); }

    for (int kc = 0; kc < NCHUNK; ++kc) {
        __syncthreads();                     // one barrier per stage
        const int cur = kc & 1;

        if (kc + 1 < NCHUNK) {               // write next stage (regs -> LDS)
            *(f4*)&sA[cur ^ 1][rs0 * PADK + cs0]        = ra;
            *(f4*)&sA[cur ^ 1][(rs0 + 32) * PADK + cs0] = rb;
        }
        if (kc + 2 < NCHUNK) {               // prefetch stage kc+2 (vmcnt-counted)
            const long ko = (long)(kc + 2) * KC;
            ra = *(const f4*)(hA + (long)rs0 * DIM + ko + cs0);
            rb = *(const f4*)(hA + (long)(rs0 + 32) * DIM + ko + cs0);
        }

        // 4 numpy 16-blocks, strictly ascending k
        #pragma unroll
        for (int s = 0; s < 4; ++s) {
            const int kb = kc * KC + s * 16;

            // B: 4 experts x 16 floats, wave-uniform -> s_load (SGPRs)
            f4 B[EPW][4];
            #pragma unroll
            for (int j = 0; j < EPW; ++j)
                #pragma unroll
                for (int q = 0; q < 4; ++q)
                    B[j][q] = *(const f4*)(wb + (long)j * DIM + kb + 4 * q);

            // A: this lane's token (4 x ds_read_b128)
            f4 af[4];
            const float* ab = &sA[cur][lane * PADK + s * 16];
            #pragma unroll
            for (int v = 0; v < 4; ++v) af[v] = *(const f4*)(ab + 4 * v);

            f2 alo[4], ahi[4];               // .xy -> chains 0,1 ; .zw -> 2,3
            #pragma unroll
            for (int v = 0; v < 4; ++v) {
                alo[v] = __builtin_shufflevector(af[v], af[v], 0, 1);
                ahi[v] = __builtin_shufflevector(af[v], af[v], 2, 3);
            }

            #pragma unroll
            for (int j = 0; j < EPW; ++j) {
                f2 blo[4], bhi[4];           // uniform values (SGPR pairs)
                #pragma unroll
                for (int v = 0; v < 4; ++v) {
                    blo[v] = __builtin_shufflevector(B[j][v], B[j][v], 0, 1);
                    bhi[v] = __builtin_shufflevector(B[j][v], B[j][v], 2, 3);
                }
                f2 t;
                // chains 0,1: c = p0 + (p1 + (p2 + (p3 + c)))
                t = pk_add(pk_mul_sv(blo[3], alo[3]), a01[j]);
                t = pk_add(pk_mul_sv(blo[2], alo[2]), t);
                t = pk_add(pk_mul_sv(blo[1], alo[1]), t);
                a01[j] = pk_add(pk_mul_sv(blo[0], alo[0]), t);
                // chains 2,3
                t = pk_add(pk_mul_sv(bhi[3], ahi[3]), a23[j]);
                t = pk_add(pk_mul_sv(bhi[2], ahi[2]), t);
                t = pk_add(pk_mul_sv(bhi[1], ahi[1]), t);
                a23[j] = pk_add(pk_mul_sv(bhi[0], ahi[0]), t);
            }
        }
    }

    // horizontal combine: (c0+c2)+(c1+c3) -> global logits
    #pragma unroll
    for (int j = 0; j < EPW; ++j) {
        f2 s2 = pk_add(a01[j], a23[j]);      // (c0+c2, c1+c3)
        lgout[(tok0 + lane) * NEXP + e0 + j] = s2.x + s2.y;
    }
}

// ---------- split path kernel 2: softmax + top-8 + aux partials ----------
// grid 256 blocks x 512 thr; wave = 8 tokens; verbatim verified numpy orders.
__global__ __launch_bounds__(512) void softmax_topk(
    const float* __restrict__ lgout, float* __restrict__ out,
    float* __restrict__ wsum)
{
    __shared__ float ls[8][NEXP + 2];
    const int tid  = threadIdx.x;
    const int lane = tid & 63;               // lane = expert
    const int wv8  = tid >> 6;               // 0..7
    const int blk  = blockIdx.x;
    const long tok0 = (long)blk * 64;
    float auxacc = 0.f;

    for (int tt = 0; tt < 8; ++tt) {
        const long gt = tok0 + wv8 * 8 + tt;
        const float s = lgout[gt * NEXP + lane];

        float m = s;                          // max: exact, order-independent
        #pragma unroll
        for (int off = 32; off >= 1; off >>= 1)
            m = fmaxf(m, __shfl_xor(m, off));

        const float p = expf(s - m);
        ls[wv8][lane] = p;                    // own wave's row only
        __asm__ volatile("" ::: "memory");    // compiler barrier; DS in-order per wave

        // np.sum pairwise, n=64: 8 stride-8 serial chains + fixed combine
        float r0s = ls[wv8][0], r1s = ls[wv8][1], r2s = ls[wv8][2], r3s = ls[wv8][3];
        float r4s = ls[wv8][4], r5s = ls[wv8][5], r6s = ls[wv8][6], r7s = ls[wv8][7];
        #pragma unroll
        for (int i = 1; i < 8; ++i) {
            r0s += ls[wv8][8 * i + 0]; r1s += ls[wv8][8 * i + 1];
            r2s += ls[wv8][8 * i + 2]; r3s += ls[wv8][8 * i + 3];
            r4s += ls[wv8][8 * i + 4]; r5s += ls[wv8][8 * i + 5];
            r6s += ls[wv8][8 * i + 6]; r7s += ls[wv8][8 * i + 7];
        }
        const float S = ((r0s + r1s) + (r2s + r3s)) + ((r4s + r5s) + (r6s + r7s));

        const float score = p / S;            // IEEE f32 divide, matches np
        auxacc += score;

        // stable top-8: max with lowest-index tie-break (stable argsort)
        float cv = score;
        float myv = 0.f;
        int   myi = 0;
        #pragma unroll
        for (int i = 0; i < TOPK; ++i) {
            float v = cv;
            int idx = lane;
            #pragma unroll
            for (int off = 32; off >= 1; off >>= 1) {
                float v2 = __shfl_xor(v, off);
                int   i2 = __shfl_xor(idx, off);
                if (v2 > v || (v2 == v && i2 < idx)) { v = v2; idx = i2; }
            }
            if (lane == i)   { myv = v; myi = idx; }
            if (lane == idx) cv = -1.f;       // scores >= 0
        }

        // weight denom: np.sum n=8 -> serial ascending
        float S8 = 0.f;
        #pragma unroll
        for (int r = 0; r < TOPK; ++r) S8 += __shfl(myv, r);

        if (lane < TOPK) {
            const long o = gt * TOPK + lane;
            out[o]                     = (float)myi;   // expert_ids
            out[(long)NTOK * TOPK + o] = myv / S8;     // expert_weight
        }
    }

    atomicAdd(&wsum[(blk >> 6) * NEXP + lane], auxacc);
}

// ---------- fallback monolith (verified R10 kernel, used if ws too small) ----------
__global__ __launch_bounds__(1024, 1) void moe_gate_np(
    const float* __restrict__ h, const float* __restrict__ W,
    float* __restrict__ out, float* __restrict__ wsum)
{
#pragma clang fp contract(off)
    __shared__ float sA[BT * PADK];
    __shared__ float lg[BT][NEXP + 2];

    const int tid  = threadIdx.x;
    const int lane = tid & 63;
    const int wv   = tid >> 6;
    const int blk  = blockIdx.x;
    const long tok0 = (long)blk * BT;
    const float* hA = h + tok0 * DIM;

    const int e0 = __builtin_amdgcn_readfirstlane(wv) * EPW;
    const float* wb = W + (long)e0 * DIM;

    const int rs = tid >> 4;
    const int cs = (tid & 15) * 4;
    f4 pa = *(const f4*)(hA + (long)rs * DIM + cs);

    f2 a01[EPW], a23[EPW];
    #pragma unroll
    for (int j = 0; j < EPW; ++j) { a01[j] = (f2)(0.f); a23[j] = (f2)(0.f); }

    for (int kc = 0; kc < NCHUNK; ++kc) {
        __syncthreads();
        *(f4*)&sA[rs * PADK + cs] = pa;
        __syncthreads();
        if (kc + 1 < NCHUNK)
            pa = *(const f4*)(hA + (long)rs * DIM + (long)(kc + 1) * KC + cs);

        #pragma unroll
        for (int s = 0; s < 4; ++s) {
            const int kb = kc * KC + s * 16;
            f4 B[EPW][4];
            #pragma unroll
            for (int j = 0; j < EPW; ++j)
                #pragma unroll
                for (int q = 0; q < 4; ++q)
                    B[j][q] = *(const f4*)(wb + (long)j * DIM + kb + 4 * q);
            f4 af[4];
            const float* ab = &sA[lane * PADK + s * 16];
            #pragma unroll
            for (int v = 0; v < 4; ++v) af[v] = *(const f4*)(ab + 4 * v);
            f2 alo[4], ahi[4];
            #pragma unroll
            for (int v = 0; v < 4; ++v) {
                alo[v] = __builtin_shufflevector(af[v], af[v], 0, 1);
                ahi[v] = __builtin_shufflevector(af[v], af[v], 2, 3);
            }
            #pragma unroll
            for (int j = 0; j < EPW; ++j) {
                f2 blo[4], bhi[4];
                #pragma unroll
                for (int v = 0; v < 4; ++v) {
                    blo[v] = __builtin_shufflevector(B[j][v], B[j][v], 0, 1);
                    bhi[v] = __builtin_shufflevector(B[j][v], B[j][v], 2, 3);
                }
                f2 t;
                t = pk_add(pk_mul_sv(blo[3], alo[3]), a01[j]);
                t = pk_add(pk_mul_sv(blo[2], alo[2]), t);
                t = pk_add(pk_mul_sv(blo[1], alo[1]), t);
                a01[j] = pk_add(pk_mul_sv(blo[0], alo[0]), t);
                t = pk_add(pk_mul_sv(bhi[3], ahi[3]), a23[j]);
                t = pk_add(pk_mul_sv(bhi[2], ahi[2]), t);
                t = pk_add(pk_mul_sv(bhi[1], ahi[1]), t);
                a23[j] = pk_add(pk_mul_sv(bhi[0], ahi[0]), t);
            }
        }
    }

    #pragma unroll
    for (int j = 0; j < EPW; ++j) {
        f2 s2 = pk_add(a01[j], a23[j]);
        lg[lane][e0 + j] = s2.x + s2.y;
    }
    __syncthreads();

    float auxacc = 0.f;
    for (int tt = 0; tt < 4; ++tt) {
        const int t = wv * 4 + tt;
        const float s = lg[t][lane];
        float m = s;
        #pragma unroll
        for (int off = 32; off >= 1; off >>= 1)
            m = fmaxf(m, __shfl_xor(m, off));
        const float p = expf(s - m);
        lg[t][lane] = p;
        __asm__ volatile("" ::: "memory");
        float r0s = lg[t][0], r1s = lg[t][1], r2s = lg[t][2], r3s = lg[t][3];
        float r4s = lg[t][4], r5s = lg[t][5], r6s = lg[t][6], r7s = lg[t][7];
        #pragma unroll
        for (int i = 1; i < 8; ++i) {
            r0s += lg[t][8 * i + 0]; r1s += lg[t][8 * i + 1];
            r2s += lg[t][8 * i + 2]; r3s += lg[t][8 * i + 3];
            r4s += lg[t][8 * i + 4]; r5s += lg[t][8 * i + 5];
            r6s += lg[t][8 * i + 6]; r7s += lg[t][8 * i + 7];
        }
        const float S = ((r0s + r1s) + (r2s + r3s)) + ((r4s + r5s) + (r6s + r7s));
        const float score = p / S;
        auxacc += score;
        float cv = score;
        float myv = 0.f;
        int   myi = 0;
        #pragma unroll
        for (int i = 0; i < TOPK; ++i) {
            float v = cv;
            int idx = lane;
            #pragma unroll
            for (int off = 32; off >= 1; off >>= 1) {
                float v2 = __shfl_xor(v, off);
                int   i2 = __shfl_xor(idx, off);
                if (v2 > v || (v2 == v && i2 < idx)) { v = v2; idx = i2; }
            }
            if (lane == i)   { myv = v; myi = idx; }
            if (lane == idx) cv = -1.f;
        }
        float S8 = 0.f;
        #pragma unroll
        for (int r = 0; r < TOPK; ++r) S8 += __shfl(myv, r);
        if (lane < TOPK) {
            const long o = (tok0 + t) * TOPK + lane;
            out[o]                     = (float)myi;
            out[(long)NTOK * TOPK + o] = myv / S8;
        }
    }
    atomicAdd(&wsum[(blk >> 6) * NEXP + lane], auxacc);
}

__global__ void aux_finish(const float* __restrict__ wsum, float* __restrict__ out)
{
    const int lane = threadIdx.x;            // 64 threads
    float a = 0.f;
    #pragma unroll
    for (int b = 0; b < 4; ++b) {
        const float v = wsum[b * NEXP + lane] * (1.0f / 4096.0f);
        a = fmaf(v, v, a);
    }
    #pragma unroll
    for (int off = 32; off >= 1; off >>= 1)
        a += __shfl_xor(a, off);
    if (lane == 0)
        out[2L * NTOK * TOPK] = a * 0.25f * (float)NEXP * 0.01f;
}

extern "C" void kernel_launch(void* const* d_in, const int* in_sizes, int n_in,
                              void* d_out, int out_size, void* d_ws, size_t ws_size,
                              hipStream_t stream) {
    const float* h = (const float*)d_in[0];
    const float* W = (const float*)d_in[1];
    float* out  = (float*)d_out;
    float* wsum = (float*)d_ws;              // 256 f32 @ offset 0

    const size_t need = 4096 + (size_t)NTOK * NEXP * sizeof(float);

    hipMemsetAsync(d_ws, 0, 1024, stream);
    if (ws_size >= need) {
        float* lgout = (float*)((char*)d_ws + 4096);   // 4 MB logits
        moe_gemm<<<(NTOK / BT) * 2, 512, 0, stream>>>(h, W, lgout);
        softmax_topk<<<NTOK / 64, 512, 0, stream>>>(lgout, out, wsum);
    } else {
        moe_gate_np<<<NTOK / BT, 1024, 0, stream>>>(h, W, out, wsum);
    }
    aux_finish<<<1, 64, 0, stream>>>(wsum, out);
}